// Round 1
// baseline (38319.577 us; speedup 1.0000x reference)
//
#include <hip/hip_runtime.h>
#include <math.h>

#define SLEN 8192
#define DIM  256
#define H2N  256
#define G4   1024
#define NTAG 16
#define NEGV (-10000.0f)

// ws layout
#define OFF_PRE_F   0
#define OFF_PRE_B   (SLEN*G4)
#define OFF_HS_F    (2*SLEN*G4)
#define OFF_HS_B    (2*SLEN*G4 + SLEN*H2N)
#define OFF_FEATS   (2*SLEN*G4 + 2*SLEN*H2N)
#define OFF_BACK_B  ((size_t)(OFF_FEATS + SLEN*NTAG) * 4)   // byte offset
#define OFF_PROG_B  (OFF_BACK_B + (size_t)SLEN*NTAG)
#define WS_NEEDED   (OFF_PROG_B + 64)

// ---------------- K1: pre = gather(emb, sentence[±]) @ w_ih^T + b ----------------
__global__ __launch_bounds__(256) void gemm_pre(
    const int* __restrict__ sent, const float* __restrict__ emb,
    const float* __restrict__ wf, const float* __restrict__ bf,
    const float* __restrict__ wb, const float* __restrict__ bb,
    float* __restrict__ pre_f, float* __restrict__ pre_b)
{
    const int dir = blockIdx.z;
    const float* w    = dir ? wb : wf;
    const float* bias = dir ? bb : bf;
    float* out        = dir ? pre_b : pre_f;
    const int m0 = blockIdx.x * 64, n0 = blockIdx.y * 64;

    __shared__ float As[64][17];
    __shared__ float Bs[64][17];
    __shared__ int   sidx[64];

    const int tid = threadIdx.x;
    const int tx = tid & 15, ty = tid >> 4;

    if (tid < 64) {
        int m = m0 + tid;
        int pos = dir ? (SLEN - 1 - m) : m;
        sidx[tid] = sent[pos];
    }
    __syncthreads();

    float acc[4][4];
#pragma unroll
    for (int i = 0; i < 4; i++)
#pragma unroll
        for (int j = 0; j < 4; j++) acc[i][j] = 0.f;

    const int lr = tid >> 2, lc = (tid & 3) * 4;

    for (int k0 = 0; k0 < DIM; k0 += 16) {
        float4 av = *(const float4*)(emb + (size_t)sidx[lr] * DIM + k0 + lc);
        float4 bv = *(const float4*)(w + (size_t)(n0 + lr) * DIM + k0 + lc);
        As[lr][lc+0] = av.x; As[lr][lc+1] = av.y; As[lr][lc+2] = av.z; As[lr][lc+3] = av.w;
        Bs[lr][lc+0] = bv.x; Bs[lr][lc+1] = bv.y; Bs[lr][lc+2] = bv.z; Bs[lr][lc+3] = bv.w;
        __syncthreads();
#pragma unroll
        for (int k = 0; k < 16; k++) {
            float a[4], b[4];
#pragma unroll
            for (int i = 0; i < 4; i++) a[i] = As[ty*4+i][k];
#pragma unroll
            for (int j = 0; j < 4; j++) b[j] = Bs[tx*4+j][k];
#pragma unroll
            for (int i = 0; i < 4; i++)
#pragma unroll
                for (int j = 0; j < 4; j++) acc[i][j] += a[i] * b[j];
        }
        __syncthreads();
    }

    float4 b4 = *(const float4*)(bias + n0 + tx*4);
#pragma unroll
    for (int i = 0; i < 4; i++) {
        float4 v;
        v.x = acc[i][0] + b4.x; v.y = acc[i][1] + b4.y;
        v.z = acc[i][2] + b4.z; v.w = acc[i][3] + b4.w;
        *(float4*)(out + (size_t)(m0 + ty*4 + i) * G4 + n0 + tx*4) = v;
    }
}

// ---------------- K2: two LSTMs, 4 CUs each, W_hh register-resident ----------------
__global__ __launch_bounds__(256, 1) void lstm_kernel(
    const float* __restrict__ pre_f, const float* __restrict__ pre_b,
    const float* __restrict__ whh_f, const float* __restrict__ whh_b,
    const float* __restrict__ h0_f, const float* __restrict__ c0_f,
    const float* __restrict__ h0_b, const float* __restrict__ c0_b,
    float* __restrict__ hs_f, float* __restrict__ hs_b, int* progress)
{
    const int blk = blockIdx.x;          // 0..7
    const int d = blk >> 2, b = blk & 3; // direction, quarter
    const float* pre = d ? pre_b : pre_f;
    const float* whh = d ? whh_b : whh_f;
    const float* h0  = d ? h0_b : h0_f;
    const float* c0  = d ? c0_b : c0_f;
    float* hs        = d ? hs_b : hs_f;

    const int tid = threadIdx.x;
    const int gate = tid >> 6, io = tid & 63;
    const int row = gate * 256 + b * 64 + io;

    // 256 weights per thread in VGPRs (64 float4)
    float4 w4[64];
    const float4* wrow = (const float4*)(whh + (size_t)row * H2N);
#pragma unroll
    for (int i = 0; i < 64; i++) w4[i] = wrow[i];

    __shared__ __align__(16) float h_lds[256];
    __shared__ float g_lds[256];
    h_lds[tid] = h0[tid];
    float c = (tid < 64) ? c0[b * 64 + tid] : 0.f;
    __syncthreads();

    const float* pre_row = pre + row;
    float pre_cur = pre_row[0];

    for (int t = 0; t < SLEN; t++) {
        // prefetch next step's pre (hide HBM latency behind this step)
        float pre_next = (t < SLEN - 1) ? pre_row[(size_t)(t + 1) * G4] : 0.f;

        float acc = pre_cur;
#pragma unroll
        for (int i = 0; i < 64; i++) {
            float4 hv = *(const float4*)(h_lds + 4 * i);
            acc += w4[i].x * hv.x + w4[i].y * hv.y + w4[i].z * hv.z + w4[i].w * hv.w;
        }
        g_lds[tid] = acc;
        __syncthreads();

        if (tid < 64) {
            float gi = g_lds[tid], gf = g_lds[64 + tid], gg = g_lds[128 + tid], go = g_lds[192 + tid];
            float i_ = 1.f / (1.f + expf(-gi));
            float f_ = 1.f / (1.f + expf(-gf));
            float g_ = tanhf(gg);
            float o_ = 1.f / (1.f + expf(-go));
            c = f_ * c + i_ * g_;
            float h = o_ * tanhf(c);
            hs[(size_t)t * H2N + b * 64 + tid] = h;
        }
        if (tid == 0) {
            __threadfence();  // drain wave0's h stores, write back L2
            __hip_atomic_store(&progress[blk], t + 1, __ATOMIC_RELEASE, __HIP_MEMORY_SCOPE_AGENT);
        }
        if (tid < 4) {
            int peer = d * 4 + tid;
            int spin = 0;
            while (__hip_atomic_load(&progress[peer], __ATOMIC_ACQUIRE, __HIP_MEMORY_SCOPE_AGENT) <= t) {
                if (++spin > 40000000) break;   // safety: no infinite hang
            }
        }
        __syncthreads();
        h_lds[tid] = hs[(size_t)t * H2N + tid];
        pre_cur = pre_next;
        __syncthreads();
    }
}

// ---------------- K3: feats = concat(hs_f[s], hs_b[S-1-s]) @ w_out^T + b_out ----------------
__global__ __launch_bounds__(256) void feats_kernel(
    const float* __restrict__ hs_f, const float* __restrict__ hs_b,
    const float* __restrict__ w_out, const float* __restrict__ b_out,
    float* __restrict__ feats)
{
    const int rs0 = blockIdx.x * 16;
    const int tid = threadIdx.x;
    const int r = tid >> 4, cc = tid & 15;

    __shared__ float Hs[16][513];
    for (int i = tid; i < 16 * 256; i += 256) {
        int rr = i >> 8, k = i & 255;
        Hs[rr][k]       = hs_f[(size_t)(rs0 + rr) * H2N + k];
        Hs[rr][256 + k] = hs_b[(size_t)(SLEN - 1 - (rs0 + rr)) * H2N + k];
    }
    __syncthreads();

    float acc = 0.f;
    const float* wr = w_out + (size_t)cc * 512;
#pragma unroll 8
    for (int k = 0; k < 512; k++) acc += Hs[r][k] * wr[k];
    feats[(size_t)(rs0 + r) * NTAG + cc] = acc + b_out[cc];
}

// ---------------- K4: Viterbi scan + backtrack (single wave) ----------------
__global__ __launch_bounds__(64) void viterbi_kernel(
    const float* __restrict__ feats, const float* __restrict__ trans,
    unsigned char* __restrict__ back, float* __restrict__ out)
{
    const int lane = threadIdx.x;
    const int nx = lane >> 2, pc = lane & 3;   // next tag, prev-chunk

    float tr[4];
#pragma unroll
    for (int j = 0; j < 4; j++) tr[j] = trans[nx * NTAG + pc * 4 + j];

    // score of tag g lives (replicated) in lanes 4g..4g+3
    float sc = (nx == 0) ? 0.f : NEGV;
    float fe = feats[nx];   // prefetch t=0

    for (int t = 0; t < SLEN; t++) {
        float fe_next = (t < SLEN - 1) ? feats[(size_t)(t + 1) * NTAG + nx] : 0.f;

        float bv; int bi;
#pragma unroll
        for (int j = 0; j < 4; j++) {
            float s = __shfl(sc, 4 * (pc * 4 + j), 64);
            float cand = s + tr[j];
            if (j == 0) { bv = cand; bi = pc * 4; }
            else if (cand > bv) { bv = cand; bi = pc * 4 + j; }
        }
        // combine across the 4 prev-chunks; first-max semantics (tie -> smaller idx)
#pragma unroll
        for (int off = 1; off < 4; off <<= 1) {
            float ov = __shfl_xor(bv, off, 64);
            int   oi = __shfl_xor(bi, off, 64);
            if (ov > bv || (ov == bv && oi < bi)) { bv = ov; bi = oi; }
        }
        if (pc == 0) back[(size_t)t * NTAG + nx] = (unsigned char)bi;
        sc = bv + fe;
        fe = fe_next;
    }

    // final = last + trans[END=1]; first-argmax
    float bestv = 0.f; int besti = 0;
#pragma unroll
    for (int j = 0; j < NTAG; j++) {
        float sj = __shfl(sc, 4 * j, 64);
        float fj = sj + trans[1 * NTAG + j];
        if (j == 0) { bestv = fj; besti = 0; }
        else if (fj > bestv) { bestv = fj; besti = j; }
    }

    if (lane == 0) {
        out[0] = bestv;
        int cur = besti;
        for (int t = SLEN - 1; t >= 1; t--) {
            out[1 + t] = (float)cur;
            cur = back[(size_t)t * NTAG + cur];
        }
        out[1] = (float)cur;
    }
}

extern "C" void kernel_launch(void* const* d_in, const int* in_sizes, int n_in,
                              void* d_out, int out_size, void* d_ws, size_t ws_size,
                              hipStream_t stream) {
    const int*   sent   = (const int*)d_in[0];
    const float* emb    = (const float*)d_in[1];
    const float* w_ih_f = (const float*)d_in[2];
    const float* w_hh_f = (const float*)d_in[3];
    const float* b_f    = (const float*)d_in[4];
    const float* w_ih_b = (const float*)d_in[5];
    const float* w_hh_b = (const float*)d_in[6];
    const float* b_b    = (const float*)d_in[7];
    const float* h0_f   = (const float*)d_in[8];
    const float* c0_f   = (const float*)d_in[9];
    const float* h0_b   = (const float*)d_in[10];
    const float* c0_b   = (const float*)d_in[11];
    const float* w_out  = (const float*)d_in[12];
    const float* b_out  = (const float*)d_in[13];
    const float* trans  = (const float*)d_in[14];
    float* out = (float*)d_out;

    if (ws_size < WS_NEEDED) return;  // visible failure, no OOB writes

    float* ws = (float*)d_ws;
    float* pre_f = ws + OFF_PRE_F;
    float* pre_b = ws + OFF_PRE_B;
    float* hs_f  = ws + OFF_HS_F;
    float* hs_b  = ws + OFF_HS_B;
    float* feats = ws + OFF_FEATS;
    unsigned char* back = (unsigned char*)d_ws + OFF_BACK_B;
    int* progress = (int*)((char*)d_ws + OFF_PROG_B);

    hipMemsetAsync(progress, 0, 32, stream);

    gemm_pre<<<dim3(128, 16, 2), 256, 0, stream>>>(sent, emb, w_ih_f, b_f, w_ih_b, b_b, pre_f, pre_b);
    lstm_kernel<<<8, 256, 0, stream>>>(pre_f, pre_b, w_hh_f, w_hh_b,
                                       h0_f, c0_f, h0_b, c0_b, hs_f, hs_b, progress);
    feats_kernel<<<512, 256, 0, stream>>>(hs_f, hs_b, w_out, b_out, feats);
    viterbi_kernel<<<1, 64, 0, stream>>>(feats, trans, back, out);
}

// Round 2
// 25836.111 us; speedup vs baseline: 1.4832x; 1.4832x over previous
//
#include <hip/hip_runtime.h>
#include <math.h>

#define SLEN 8192
#define DIM  256
#define H2N  256
#define G4   1024
#define NTAG 16
#define NEGV (-10000.0f)

// ws layout (floats unless noted)
#define OFF_PRE_F   0
#define OFF_PRE_B   (SLEN*G4)
#define OFF_HS_F    (2*SLEN*G4)
#define OFF_HS_B    (2*SLEN*G4 + SLEN*H2N)
#define OFF_FEATS   (2*SLEN*G4 + 2*SLEN*H2N)
#define OFF_BACK_B  ((size_t)(OFF_FEATS + SLEN*NTAG) * 4)   // byte offset
#define WS_NEEDED   (OFF_BACK_B + (size_t)SLEN*NTAG)

// ---------------- K1: pre = gather(emb, sentence[±]) @ w_ih^T + b ----------------
__global__ __launch_bounds__(256) void gemm_pre(
    const int* __restrict__ sent, const float* __restrict__ emb,
    const float* __restrict__ wf, const float* __restrict__ bf,
    const float* __restrict__ wb, const float* __restrict__ bb,
    float* __restrict__ pre_f, float* __restrict__ pre_b)
{
    const int dir = blockIdx.z;
    const float* w    = dir ? wb : wf;
    const float* bias = dir ? bb : bf;
    float* out        = dir ? pre_b : pre_f;
    const int m0 = blockIdx.x * 64, n0 = blockIdx.y * 64;

    __shared__ float As[64][17];
    __shared__ float Bs[64][17];
    __shared__ int   sidx[64];

    const int tid = threadIdx.x;
    const int tx = tid & 15, ty = tid >> 4;

    if (tid < 64) {
        int m = m0 + tid;
        int pos = dir ? (SLEN - 1 - m) : m;
        sidx[tid] = sent[pos];
    }
    __syncthreads();

    float acc[4][4];
#pragma unroll
    for (int i = 0; i < 4; i++)
#pragma unroll
        for (int j = 0; j < 4; j++) acc[i][j] = 0.f;

    const int lr = tid >> 2, lc = (tid & 3) * 4;

    for (int k0 = 0; k0 < DIM; k0 += 16) {
        float4 av = *(const float4*)(emb + (size_t)sidx[lr] * DIM + k0 + lc);
        float4 bv = *(const float4*)(w + (size_t)(n0 + lr) * DIM + k0 + lc);
        As[lr][lc+0] = av.x; As[lr][lc+1] = av.y; As[lr][lc+2] = av.z; As[lr][lc+3] = av.w;
        Bs[lr][lc+0] = bv.x; Bs[lr][lc+1] = bv.y; Bs[lr][lc+2] = bv.z; Bs[lr][lc+3] = bv.w;
        __syncthreads();
#pragma unroll
        for (int k = 0; k < 16; k++) {
            float a[4], b[4];
#pragma unroll
            for (int i = 0; i < 4; i++) a[i] = As[ty*4+i][k];
#pragma unroll
            for (int j = 0; j < 4; j++) b[j] = Bs[tx*4+j][k];
#pragma unroll
            for (int i = 0; i < 4; i++)
#pragma unroll
                for (int j = 0; j < 4; j++) acc[i][j] += a[i] * b[j];
        }
        __syncthreads();
    }

    float4 b4 = *(const float4*)(bias + n0 + tx*4);
#pragma unroll
    for (int i = 0; i < 4; i++) {
        float4 v;
        v.x = acc[i][0] + b4.x; v.y = acc[i][1] + b4.y;
        v.z = acc[i][2] + b4.z; v.w = acc[i][3] + b4.w;
        *(float4*)(out + (size_t)(m0 + ty*4 + i) * G4 + n0 + tx*4) = v;
    }
}

// ---------------- K2: two LSTMs, 4 CUs each, W_hh register-resident ----------------
// Sync protocol: data-as-flag. h is stored with mantissa bit0 forced to 1
// (<=1 ulp error) via system-scope relaxed stores (bypass L1/L2 -> LLC).
// Peers spin on their own dword with system-scope relaxed loads until bit0
// is set. One fabric round trip per step; no fences, no counters, no ABA
// (every (t, element) address is written exactly once; ws is poisoned 0xAA
// before each launch, and 0xAAAAAAAA has bit0 == 0).
__global__ __attribute__((amdgpu_flat_work_group_size(256, 256), amdgpu_waves_per_eu(1, 1)))
void lstm_kernel(
    const float* __restrict__ pre_f, const float* __restrict__ pre_b,
    const float* __restrict__ whh_f, const float* __restrict__ whh_b,
    const float* __restrict__ h0_f, const float* __restrict__ c0_f,
    const float* __restrict__ h0_b, const float* __restrict__ c0_b,
    float* __restrict__ hs_f, float* __restrict__ hs_b)
{
    const int blk = blockIdx.x;          // 0..7
    const int d = blk >> 2, b = blk & 3; // direction, quarter
    const float* pre = d ? pre_b : pre_f;
    const float* whh = d ? whh_b : whh_f;
    const float* h0  = d ? h0_b : h0_f;
    const float* c0  = d ? c0_b : c0_f;
    float* hs        = d ? hs_b : hs_f;

    const int tid = threadIdx.x;
    const int q = tid >> 6, io = tid & 63;     // wave id, lane
    const int row = q * 256 + b * 64 + io;     // this thread's gate row

    // 256 f32 weights per thread, split into 4 arrays of 16 float4 to keep
    // SROA happy; waves_per_eu(1,1) gives the allocator the full 512-VGPR
    // budget so these stay register-resident (check VGPR_Count ~300).
    float4 wA[16], wB[16], wC[16], wD[16];
    const float4* wrow = (const float4*)(whh + (size_t)row * H2N);
#pragma unroll
    for (int j = 0; j < 16; j++) wA[j] = wrow[j];
#pragma unroll
    for (int j = 0; j < 16; j++) wB[j] = wrow[16 + j];
#pragma unroll
    for (int j = 0; j < 16; j++) wC[j] = wrow[32 + j];
#pragma unroll
    for (int j = 0; j < 16; j++) wD[j] = wrow[48 + j];

    __shared__ __align__(16) float h_lds[256];
    __shared__ float g_lds[256];
    h_lds[tid] = h0[tid];
    float c = (tid < 64) ? c0[b * 64 + tid] : 0.f;
    __syncthreads();

    const float* pre_row = pre + row;
    float pre_cur = pre_row[0];
    const int qq = (b + q) & 3;   // quarter this wave polls (waves 1..3)

    for (int t = 0; t < SLEN; t++) {
        float pre_next = (t < SLEN - 1) ? pre_row[(size_t)(t + 1) * G4] : 0.f;

        // dot: 4 independent accumulator chains, broadcast b128 LDS reads
        float a0 = pre_cur, a1 = 0.f, a2 = 0.f, a3 = 0.f;
        const float4* hv = (const float4*)h_lds;
#pragma unroll
        for (int j = 0; j < 16; j++) {
            float4 h0v = hv[j];
            float4 h1v = hv[16 + j];
            float4 h2v = hv[32 + j];
            float4 h3v = hv[48 + j];
            a0 += wA[j].x * h0v.x + wA[j].y * h0v.y + wA[j].z * h0v.z + wA[j].w * h0v.w;
            a1 += wB[j].x * h1v.x + wB[j].y * h1v.y + wB[j].z * h1v.z + wB[j].w * h1v.w;
            a2 += wC[j].x * h2v.x + wC[j].y * h2v.y + wC[j].z * h2v.z + wC[j].w * h2v.w;
            a3 += wD[j].x * h3v.x + wD[j].y * h3v.y + wD[j].z * h3v.z + wD[j].w * h3v.w;
        }
        g_lds[tid] = (a0 + a1) + (a2 + a3);
        __syncthreads();

        if (q == 0) {
            // wave 0: activation for our quarter's 64 cells + publish h
            float gi = g_lds[io], gf = g_lds[64 + io], gg = g_lds[128 + io], go = g_lds[192 + io];
            float i_ = 1.f / (1.f + expf(-gi));
            float f_ = 1.f / (1.f + expf(-gf));
            float g_ = tanhf(gg);
            float o_ = 1.f / (1.f + expf(-go));
            c = f_ * c + i_ * g_;
            float h = o_ * tanhf(c);
            unsigned hm = __float_as_uint(h) | 1u;      // flag bit, <=1 ulp
            h_lds[b * 64 + io] = __uint_as_float(hm);
            __hip_atomic_store((unsigned*)hs + (size_t)t * H2N + b * 64 + io, hm,
                               __ATOMIC_RELAXED, __HIP_MEMORY_SCOPE_SYSTEM);
        } else {
            // waves 1..3: pull one remote quarter, spinning on own dword
            const unsigned* src = (const unsigned*)hs + (size_t)t * H2N + qq * 64 + io;
            unsigned v; int spin = 0;
            do {
                v = __hip_atomic_load(src, __ATOMIC_RELAXED, __HIP_MEMORY_SCOPE_SYSTEM);
            } while (!(v & 1u) && ++spin < 50000000);
            h_lds[qq * 64 + io] = __uint_as_float(v);
        }
        __syncthreads();
        pre_cur = pre_next;
    }
}

// ---------------- K3: feats = concat(hs_f[s], hs_b[S-1-s]) @ w_out^T + b_out ----------------
__global__ __launch_bounds__(256) void feats_kernel(
    const float* __restrict__ hs_f, const float* __restrict__ hs_b,
    const float* __restrict__ w_out, const float* __restrict__ b_out,
    float* __restrict__ feats)
{
    const int rs0 = blockIdx.x * 16;
    const int tid = threadIdx.x;
    const int r = tid >> 4, cc = tid & 15;

    __shared__ float Hs[16][513];
    for (int i = tid; i < 16 * 256; i += 256) {
        int rr = i >> 8, k = i & 255;
        Hs[rr][k]       = hs_f[(size_t)(rs0 + rr) * H2N + k];
        Hs[rr][256 + k] = hs_b[(size_t)(SLEN - 1 - (rs0 + rr)) * H2N + k];
    }
    __syncthreads();

    float acc = 0.f;
    const float* wr = w_out + (size_t)cc * 512;
#pragma unroll 8
    for (int k = 0; k < 512; k++) acc += Hs[r][k] * wr[k];
    feats[(size_t)(rs0 + r) * NTAG + cc] = acc + b_out[cc];
}

// ---------------- K4: Viterbi scan + backtrack (single wave) ----------------
__global__ __launch_bounds__(64) void viterbi_kernel(
    const float* __restrict__ feats, const float* __restrict__ trans,
    unsigned char* __restrict__ back, float* __restrict__ out)
{
    const int lane = threadIdx.x;
    const int nx = lane >> 2, pc = lane & 3;   // next tag, prev-chunk

    float tr[4];
#pragma unroll
    for (int j = 0; j < 4; j++) tr[j] = trans[nx * NTAG + pc * 4 + j];

    // score of tag g lives (replicated) in lanes 4g..4g+3
    float sc = (nx == 0) ? 0.f : NEGV;
    float fe = feats[nx];   // prefetch t=0

    for (int t = 0; t < SLEN; t++) {
        float fe_next = (t < SLEN - 1) ? feats[(size_t)(t + 1) * NTAG + nx] : 0.f;

        float bv; int bi;
#pragma unroll
        for (int j = 0; j < 4; j++) {
            float s = __shfl(sc, 4 * (pc * 4 + j), 64);
            float cand = s + tr[j];
            if (j == 0) { bv = cand; bi = pc * 4; }
            else if (cand > bv) { bv = cand; bi = pc * 4 + j; }
        }
        // combine across the 4 prev-chunks; first-max semantics (tie -> smaller idx)
#pragma unroll
        for (int off = 1; off < 4; off <<= 1) {
            float ov = __shfl_xor(bv, off, 64);
            int   oi = __shfl_xor(bi, off, 64);
            if (ov > bv || (ov == bv && oi < bi)) { bv = ov; bi = oi; }
        }
        if (pc == 0) back[(size_t)t * NTAG + nx] = (unsigned char)bi;
        sc = bv + fe;
        fe = fe_next;
    }

    // final = last + trans[END=1]; first-argmax
    float bestv = 0.f; int besti = 0;
#pragma unroll
    for (int j = 0; j < NTAG; j++) {
        float sj = __shfl(sc, 4 * j, 64);
        float fj = sj + trans[1 * NTAG + j];
        if (j == 0) { bestv = fj; besti = 0; }
        else if (fj > bestv) { bestv = fj; besti = j; }
    }

    if (lane == 0) {
        out[0] = bestv;
        int cur = besti;
        for (int t = SLEN - 1; t >= 1; t--) {
            out[1 + t] = (float)cur;
            cur = back[(size_t)t * NTAG + cur];
        }
        out[1] = (float)cur;
    }
}

extern "C" void kernel_launch(void* const* d_in, const int* in_sizes, int n_in,
                              void* d_out, int out_size, void* d_ws, size_t ws_size,
                              hipStream_t stream) {
    const int*   sent   = (const int*)d_in[0];
    const float* emb    = (const float*)d_in[1];
    const float* w_ih_f = (const float*)d_in[2];
    const float* w_hh_f = (const float*)d_in[3];
    const float* b_f    = (const float*)d_in[4];
    const float* w_ih_b = (const float*)d_in[5];
    const float* w_hh_b = (const float*)d_in[6];
    const float* b_b    = (const float*)d_in[7];
    const float* h0_f   = (const float*)d_in[8];
    const float* c0_f   = (const float*)d_in[9];
    const float* h0_b   = (const float*)d_in[10];
    const float* c0_b   = (const float*)d_in[11];
    const float* w_out  = (const float*)d_in[12];
    const float* b_out  = (const float*)d_in[13];
    const float* trans  = (const float*)d_in[14];
    float* out = (float*)d_out;

    if (ws_size < WS_NEEDED) return;  // visible failure, no OOB writes

    float* ws = (float*)d_ws;
    float* pre_f = ws + OFF_PRE_F;
    float* pre_b = ws + OFF_PRE_B;
    float* hs_f  = ws + OFF_HS_F;
    float* hs_b  = ws + OFF_HS_B;
    float* feats = ws + OFF_FEATS;
    unsigned char* back = (unsigned char*)d_ws + OFF_BACK_B;

    gemm_pre<<<dim3(128, 16, 2), 256, 0, stream>>>(sent, emb, w_ih_f, b_f, w_ih_b, b_b, pre_f, pre_b);
    lstm_kernel<<<8, 256, 0, stream>>>(pre_f, pre_b, w_hh_f, w_hh_b,
                                       h0_f, c0_f, h0_b, c0_b, hs_f, hs_b);
    feats_kernel<<<512, 256, 0, stream>>>(hs_f, hs_b, w_out, b_out, feats);
    viterbi_kernel<<<1, 64, 0, stream>>>(feats, trans, back, out);
}

// Round 3
// 25069.893 us; speedup vs baseline: 1.5285x; 1.0306x over previous
//
#include <hip/hip_runtime.h>
#include <math.h>

#define SLEN 8192
#define DIM  256
#define H2N  256
#define G4   1024
#define NTAG 16
#define NEGV (-10000.0f)

// ws layout (floats unless noted)
#define OFF_PRE_F   0
#define OFF_PRE_B   (SLEN*G4)
#define OFF_HS_F    (2*SLEN*G4)
#define OFF_HS_B    (2*SLEN*G4 + SLEN*H2N)
#define OFF_FEATS   (2*SLEN*G4 + 2*SLEN*H2N)
#define OFF_BACK_B  ((size_t)(OFF_FEATS + SLEN*NTAG) * 4)   // byte offset
#define WS_NEEDED   (OFF_BACK_B + (size_t)SLEN*NTAG)

// ---------------- K1: pre = gather(emb, sentence[±]) @ w_ih^T + b ----------------
__global__ __launch_bounds__(256) void gemm_pre(
    const int* __restrict__ sent, const float* __restrict__ emb,
    const float* __restrict__ wf, const float* __restrict__ bf,
    const float* __restrict__ wb, const float* __restrict__ bb,
    float* __restrict__ pre_f, float* __restrict__ pre_b)
{
    const int dir = blockIdx.z;
    const float* w    = dir ? wb : wf;
    const float* bias = dir ? bb : bf;
    float* out        = dir ? pre_b : pre_f;
    const int m0 = blockIdx.x * 64, n0 = blockIdx.y * 64;

    __shared__ float As[64][17];
    __shared__ float Bs[64][17];
    __shared__ int   sidx[64];

    const int tid = threadIdx.x;
    const int tx = tid & 15, ty = tid >> 4;

    if (tid < 64) {
        int m = m0 + tid;
        int pos = dir ? (SLEN - 1 - m) : m;
        sidx[tid] = sent[pos];
    }
    __syncthreads();

    float acc[4][4];
#pragma unroll
    for (int i = 0; i < 4; i++)
#pragma unroll
        for (int j = 0; j < 4; j++) acc[i][j] = 0.f;

    const int lr = tid >> 2, lc = (tid & 3) * 4;

    for (int k0 = 0; k0 < DIM; k0 += 16) {
        float4 av = *(const float4*)(emb + (size_t)sidx[lr] * DIM + k0 + lc);
        float4 bv = *(const float4*)(w + (size_t)(n0 + lr) * DIM + k0 + lc);
        As[lr][lc+0] = av.x; As[lr][lc+1] = av.y; As[lr][lc+2] = av.z; As[lr][lc+3] = av.w;
        Bs[lr][lc+0] = bv.x; Bs[lr][lc+1] = bv.y; Bs[lr][lc+2] = bv.z; Bs[lr][lc+3] = bv.w;
        __syncthreads();
#pragma unroll
        for (int k = 0; k < 16; k++) {
            float a[4], b[4];
#pragma unroll
            for (int i = 0; i < 4; i++) a[i] = As[ty*4+i][k];
#pragma unroll
            for (int j = 0; j < 4; j++) b[j] = Bs[tx*4+j][k];
#pragma unroll
            for (int i = 0; i < 4; i++)
#pragma unroll
                for (int j = 0; j < 4; j++) acc[i][j] += a[i] * b[j];
        }
        __syncthreads();
    }

    float4 b4 = *(const float4*)(bias + n0 + tx*4);
#pragma unroll
    for (int i = 0; i < 4; i++) {
        float4 v;
        v.x = acc[i][0] + b4.x; v.y = acc[i][1] + b4.y;
        v.z = acc[i][2] + b4.z; v.w = acc[i][3] + b4.w;
        *(float4*)(out + (size_t)(m0 + ty*4 + i) * G4 + n0 + tx*4) = v;
    }
}

__device__ __forceinline__ float fast_sigmoid(float x) {
    return 1.f / (1.f + __expf(-x));
}
__device__ __forceinline__ float fast_tanh(float x) {
    float xc = fminf(fmaxf(x, -15.f), 15.f);
    float e = __expf(2.f * xc);
    return (e - 1.f) / (e + 1.f);
}

// ---------------- K2: two LSTMs, 4 CUs each, W_hh register-resident ----------------
// Sync: data-as-flag. h stored with mantissa bit0 = 1 (<=1 ulp) via
// agent-scope relaxed stores; peers spin on their own dword. Monotone fresh
// addresses per t -> no ABA; ws poison 0xAA has bit0 == 0.
// Weight residency: 256 f32/thread loaded once, then passed through an
// empty asm "+v" barrier -> opaque producer, compiler cannot rematerialize
// the global loads inside the t-loop (R2: VGPR=172 + FETCH=83GB proved it
// was re-reading 256KB/step). waves_per_eu(1,1) grants the 512-VGPR budget.
__global__ __attribute__((amdgpu_flat_work_group_size(256, 256), amdgpu_waves_per_eu(1, 1)))
void lstm_kernel(
    const float* __restrict__ pre_f, const float* __restrict__ pre_b,
    const float* __restrict__ whh_f, const float* __restrict__ whh_b,
    const float* __restrict__ h0_f, const float* __restrict__ c0_f,
    const float* __restrict__ h0_b, const float* __restrict__ c0_b,
    float* __restrict__ hs_f, float* __restrict__ hs_b)
{
    const int blk = blockIdx.x;          // 0..7
    const int d = blk >> 2, b = blk & 3; // direction, quarter
    const float* pre = d ? pre_b : pre_f;
    const float* whh = d ? whh_b : whh_f;
    const float* h0  = d ? h0_b : h0_f;
    const float* c0  = d ? c0_b : c0_f;
    float* hs        = d ? hs_b : hs_f;

    const int tid = threadIdx.x;
    const int q = tid >> 6, io = tid & 63;     // wave id, lane
    const int row = q * 256 + b * 64 + io;     // this thread's gate row

    // ---- one-time weight load: 256 f32 = 256 VGPRs per thread ----
    float w0[64], w1[64], w2[64], w3[64];
    {
        const float4* wrow = (const float4*)(whh + (size_t)row * H2N);
#pragma unroll
        for (int j = 0; j < 16; j++) {
            float4 v = wrow[j];
            w0[4*j] = v.x; w0[4*j+1] = v.y; w0[4*j+2] = v.z; w0[4*j+3] = v.w;
        }
#pragma unroll
        for (int j = 0; j < 16; j++) {
            float4 v = wrow[16 + j];
            w1[4*j] = v.x; w1[4*j+1] = v.y; w1[4*j+2] = v.z; w1[4*j+3] = v.w;
        }
#pragma unroll
        for (int j = 0; j < 16; j++) {
            float4 v = wrow[32 + j];
            w2[4*j] = v.x; w2[4*j+1] = v.y; w2[4*j+2] = v.z; w2[4*j+3] = v.w;
        }
#pragma unroll
        for (int j = 0; j < 16; j++) {
            float4 v = wrow[48 + j];
            w3[4*j] = v.x; w3[4*j+1] = v.y; w3[4*j+2] = v.z; w3[4*j+3] = v.w;
        }
    }
    // opaque producer: forbids rematerialization of the loads above
#pragma unroll
    for (int j = 0; j < 64; j++) {
        asm volatile("" : "+v"(w0[j]), "+v"(w1[j]), "+v"(w2[j]), "+v"(w3[j]));
    }

    __shared__ __align__(16) float h_lds[256];
    __shared__ float g_lds[256];
    h_lds[tid] = h0[tid];
    float c = (tid < 64) ? c0[b * 64 + tid] : 0.f;
    __syncthreads();

    const float* pre_row = pre + row;
    float pre_cur = pre_row[0];
    const int qq = (b + q) & 3;   // quarter this wave polls (waves 1..3)

    for (int t = 0; t < SLEN; t++) {
        float pre_next = (t < SLEN - 1) ? pre_row[(size_t)(t + 1) * G4] : 0.f;

        // dot: 4 independent accumulator chains, broadcast b128 LDS reads
        float a0 = pre_cur, a1 = 0.f, a2 = 0.f, a3 = 0.f;
        const float4* hv = (const float4*)h_lds;
#pragma unroll
        for (int j = 0; j < 16; j++) {
            float4 h0v = hv[j];
            float4 h1v = hv[16 + j];
            float4 h2v = hv[32 + j];
            float4 h3v = hv[48 + j];
            a0 += w0[4*j] * h0v.x + w0[4*j+1] * h0v.y + w0[4*j+2] * h0v.z + w0[4*j+3] * h0v.w;
            a1 += w1[4*j] * h1v.x + w1[4*j+1] * h1v.y + w1[4*j+2] * h1v.z + w1[4*j+3] * h1v.w;
            a2 += w2[4*j] * h2v.x + w2[4*j+1] * h2v.y + w2[4*j+2] * h2v.z + w2[4*j+3] * h2v.w;
            a3 += w3[4*j] * h3v.x + w3[4*j+1] * h3v.y + w3[4*j+2] * h3v.z + w3[4*j+3] * h3v.w;
        }
        g_lds[tid] = (a0 + a1) + (a2 + a3);
        __syncthreads();

        if (q == 0) {
            // wave 0: activation for our quarter's 64 cells + publish h
            float gi = g_lds[io], gf = g_lds[64 + io], gg = g_lds[128 + io], go = g_lds[192 + io];
            float i_ = fast_sigmoid(gi);
            float f_ = fast_sigmoid(gf);
            float g_ = fast_tanh(gg);
            float o_ = fast_sigmoid(go);
            c = f_ * c + i_ * g_;
            float h = o_ * fast_tanh(c);
            unsigned hm = __float_as_uint(h) | 1u;      // flag bit, <=1 ulp
            h_lds[b * 64 + io] = __uint_as_float(hm);
            __hip_atomic_store((unsigned*)hs + (size_t)t * H2N + b * 64 + io, hm,
                               __ATOMIC_RELAXED, __HIP_MEMORY_SCOPE_AGENT);
        } else {
            // waves 1..3: pull one remote quarter, spinning on own dword
            const unsigned* src = (const unsigned*)hs + (size_t)t * H2N + qq * 64 + io;
            unsigned v; int spin = 0;
            do {
                v = __hip_atomic_load(src, __ATOMIC_RELAXED, __HIP_MEMORY_SCOPE_AGENT);
            } while (!(v & 1u) && ++spin < 20000000);
            h_lds[qq * 64 + io] = __uint_as_float(v);
        }
        __syncthreads();
        pre_cur = pre_next;
    }
}

// ---------------- K3: feats = concat(hs_f[s], hs_b[S-1-s]) @ w_out^T + b_out ----------------
__global__ __launch_bounds__(256) void feats_kernel(
    const float* __restrict__ hs_f, const float* __restrict__ hs_b,
    const float* __restrict__ w_out, const float* __restrict__ b_out,
    float* __restrict__ feats)
{
    const int rs0 = blockIdx.x * 16;
    const int tid = threadIdx.x;
    const int r = tid >> 4, cc = tid & 15;

    __shared__ float Hs[16][513];
    for (int i = tid; i < 16 * 256; i += 256) {
        int rr = i >> 8, k = i & 255;
        Hs[rr][k]       = hs_f[(size_t)(rs0 + rr) * H2N + k];
        Hs[rr][256 + k] = hs_b[(size_t)(SLEN - 1 - (rs0 + rr)) * H2N + k];
    }
    __syncthreads();

    float acc = 0.f;
    const float* wr = w_out + (size_t)cc * 512;
#pragma unroll 8
    for (int k = 0; k < 512; k++) acc += Hs[r][k] * wr[k];
    feats[(size_t)(rs0 + r) * NTAG + cc] = acc + b_out[cc];
}

// ---------------- K4: Viterbi scan + backtrack (single wave) ----------------
__global__ __launch_bounds__(64) void viterbi_kernel(
    const float* __restrict__ feats, const float* __restrict__ trans,
    unsigned char* __restrict__ back, float* __restrict__ out)
{
    const int lane = threadIdx.x;
    const int nx = lane >> 2, pc = lane & 3;   // next tag, prev-chunk

    float tr[4];
#pragma unroll
    for (int j = 0; j < 4; j++) tr[j] = trans[nx * NTAG + pc * 4 + j];

    // score of tag g lives (replicated) in lanes 4g..4g+3
    float sc = (nx == 0) ? 0.f : NEGV;
    float fe = feats[nx];   // prefetch t=0

    for (int t = 0; t < SLEN; t++) {
        float fe_next = (t < SLEN - 1) ? feats[(size_t)(t + 1) * NTAG + nx] : 0.f;

        float bv; int bi;
#pragma unroll
        for (int j = 0; j < 4; j++) {
            float s = __shfl(sc, 4 * (pc * 4 + j), 64);
            float cand = s + tr[j];
            if (j == 0) { bv = cand; bi = pc * 4; }
            else if (cand > bv) { bv = cand; bi = pc * 4 + j; }
        }
        // combine across the 4 prev-chunks; first-max semantics (tie -> smaller idx)
#pragma unroll
        for (int off = 1; off < 4; off <<= 1) {
            float ov = __shfl_xor(bv, off, 64);
            int   oi = __shfl_xor(bi, off, 64);
            if (ov > bv || (ov == bv && oi < bi)) { bv = ov; bi = oi; }
        }
        if (pc == 0) back[(size_t)t * NTAG + nx] = (unsigned char)bi;
        sc = bv + fe;
        fe = fe_next;
    }

    // final = last + trans[END=1]; first-argmax
    float bestv = 0.f; int besti = 0;
#pragma unroll
    for (int j = 0; j < NTAG; j++) {
        float sj = __shfl(sc, 4 * j, 64);
        float fj = sj + trans[1 * NTAG + j];
        if (j == 0) { bestv = fj; besti = 0; }
        else if (fj > bestv) { bestv = fj; besti = j; }
    }

    if (lane == 0) {
        out[0] = bestv;
        int cur = besti;
        for (int t = SLEN - 1; t >= 1; t--) {
            out[1 + t] = (float)cur;
            cur = back[(size_t)t * NTAG + cur];
        }
        out[1] = (float)cur;
    }
}

extern "C" void kernel_launch(void* const* d_in, const int* in_sizes, int n_in,
                              void* d_out, int out_size, void* d_ws, size_t ws_size,
                              hipStream_t stream) {
    const int*   sent   = (const int*)d_in[0];
    const float* emb    = (const float*)d_in[1];
    const float* w_ih_f = (const float*)d_in[2];
    const float* w_hh_f = (const float*)d_in[3];
    const float* b_f    = (const float*)d_in[4];
    const float* w_ih_b = (const float*)d_in[5];
    const float* w_hh_b = (const float*)d_in[6];
    const float* b_b    = (const float*)d_in[7];
    const float* h0_f   = (const float*)d_in[8];
    const float* c0_f   = (const float*)d_in[9];
    const float* h0_b   = (const float*)d_in[10];
    const float* c0_b   = (const float*)d_in[11];
    const float* w_out  = (const float*)d_in[12];
    const float* b_out  = (const float*)d_in[13];
    const float* trans  = (const float*)d_in[14];
    float* out = (float*)d_out;

    if (ws_size < WS_NEEDED) return;  // visible failure, no OOB writes

    float* ws = (float*)d_ws;
    float* pre_f = ws + OFF_PRE_F;
    float* pre_b = ws + OFF_PRE_B;
    float* hs_f  = ws + OFF_HS_F;
    float* hs_b  = ws + OFF_HS_B;
    float* feats = ws + OFF_FEATS;
    unsigned char* back = (unsigned char*)d_ws + OFF_BACK_B;

    gemm_pre<<<dim3(128, 16, 2), 256, 0, stream>>>(sent, emb, w_ih_f, b_f, w_ih_b, b_b, pre_f, pre_b);
    lstm_kernel<<<8, 256, 0, stream>>>(pre_f, pre_b, w_hh_f, w_hh_b,
                                       h0_f, c0_f, h0_b, c0_b, hs_f, hs_b);
    feats_kernel<<<512, 256, 0, stream>>>(hs_f, hs_b, w_out, b_out, feats);
    viterbi_kernel<<<1, 64, 0, stream>>>(feats, trans, back, out);
}

// Round 4
// 22906.128 us; speedup vs baseline: 1.6729x; 1.0945x over previous
//
#include <hip/hip_runtime.h>
#include <math.h>

#define SLEN 8192
#define DIM  256
#define H2N  256
#define G4   1024
#define NTAG 16
#define NEGV (-10000.0f)

// ws layout (floats unless noted)
#define OFF_PRE_F   0
#define OFF_PRE_B   (SLEN*G4)
#define OFF_HS_F    (2*SLEN*G4)
#define OFF_HS_B    (2*SLEN*G4 + SLEN*H2N)
#define OFF_FEATS   (2*SLEN*G4 + 2*SLEN*H2N)
#define OFF_BACK_B  ((size_t)(OFF_FEATS + SLEN*NTAG) * 4)   // byte offset
#define WS_NEEDED   (OFF_BACK_B + (size_t)SLEN*NTAG)

// ---------------- K1: pre = gather(emb, sentence[±]) @ w_ih^T + b ----------------
__global__ __launch_bounds__(256) void gemm_pre(
    const int* __restrict__ sent, const float* __restrict__ emb,
    const float* __restrict__ wf, const float* __restrict__ bf,
    const float* __restrict__ wb, const float* __restrict__ bb,
    float* __restrict__ pre_f, float* __restrict__ pre_b)
{
    const int dir = blockIdx.z;
    const float* w    = dir ? wb : wf;
    const float* bias = dir ? bb : bf;
    float* out        = dir ? pre_b : pre_f;
    const int m0 = blockIdx.x * 64, n0 = blockIdx.y * 64;

    __shared__ float As[64][17];
    __shared__ float Bs[64][17];
    __shared__ int   sidx[64];

    const int tid = threadIdx.x;
    const int tx = tid & 15, ty = tid >> 4;

    if (tid < 64) {
        int m = m0 + tid;
        int pos = dir ? (SLEN - 1 - m) : m;
        sidx[tid] = sent[pos];
    }
    __syncthreads();

    float acc[4][4];
#pragma unroll
    for (int i = 0; i < 4; i++)
#pragma unroll
        for (int j = 0; j < 4; j++) acc[i][j] = 0.f;

    const int lr = tid >> 2, lc = (tid & 3) * 4;

    for (int k0 = 0; k0 < DIM; k0 += 16) {
        float4 av = *(const float4*)(emb + (size_t)sidx[lr] * DIM + k0 + lc);
        float4 bv = *(const float4*)(w + (size_t)(n0 + lr) * DIM + k0 + lc);
        As[lr][lc+0] = av.x; As[lr][lc+1] = av.y; As[lr][lc+2] = av.z; As[lr][lc+3] = av.w;
        Bs[lr][lc+0] = bv.x; Bs[lr][lc+1] = bv.y; Bs[lr][lc+2] = bv.z; Bs[lr][lc+3] = bv.w;
        __syncthreads();
#pragma unroll
        for (int k = 0; k < 16; k++) {
            float a[4], b[4];
#pragma unroll
            for (int i = 0; i < 4; i++) a[i] = As[ty*4+i][k];
#pragma unroll
            for (int j = 0; j < 4; j++) b[j] = Bs[tx*4+j][k];
#pragma unroll
            for (int i = 0; i < 4; i++)
#pragma unroll
                for (int j = 0; j < 4; j++) acc[i][j] += a[i] * b[j];
        }
        __syncthreads();
    }

    float4 b4 = *(const float4*)(bias + n0 + tx*4);
#pragma unroll
    for (int i = 0; i < 4; i++) {
        float4 v;
        v.x = acc[i][0] + b4.x; v.y = acc[i][1] + b4.y;
        v.z = acc[i][2] + b4.z; v.w = acc[i][3] + b4.w;
        *(float4*)(out + (size_t)(m0 + ty*4 + i) * G4 + n0 + tx*4) = v;
    }
}

__device__ __forceinline__ float fast_sigmoid(float x) {
    return 1.f / (1.f + __expf(-x));
}
__device__ __forceinline__ float fast_tanh(float x) {
    float xc = fminf(fmaxf(x, -15.f), 15.f);
    float e = __expf(2.f * xc);
    return (e - 1.f) / (e + 1.f);
}

// ---------------- K2: two LSTMs, 32 blocks/direction, W in LDS ----------------
// R2/R3 lesson: the compiler refuses to keep 256 f32/thread in VGPRs
// (VGPR_Count pinned at 172, FETCH 82 GB = W re-read 1.25 MB/block-step).
// Fix: explicit residency. 64 blocks x 64 threads (1 wave). Each block owns
// 8 cells (32 gate rows); W slice = 32 KB f32 in LDS, loaded once.
// Row stride 260 dwords: 16B-aligned and bank-even (8 accesses/bank).
// Single wave => no __syncthreads in the hot loop except an lgkm-wait one;
// gate sums gathered by shuffle. Sync across blocks: data-as-flag (bit0=1,
// <=1 ulp) agent-scope relaxed store/load; each lane polls 4 cells as 4
// independent dword atomic loads (x4 vector load could spin on stale L2).
__global__ __launch_bounds__(64) void lstm_kernel(
    const float* __restrict__ pre_f, const float* __restrict__ pre_b,
    const float* __restrict__ whh_f, const float* __restrict__ whh_b,
    const float* __restrict__ h0_f, const float* __restrict__ c0_f,
    const float* __restrict__ h0_b, const float* __restrict__ c0_b,
    float* __restrict__ hs_f, float* __restrict__ hs_b)
{
    const int blk = blockIdx.x;            // 0..63
    const int d = blk >> 5, cb = blk & 31; // direction, cell-block
    const int cell0 = cb * 8;
    const float* pre = d ? pre_b : pre_f;
    const float* whh = d ? whh_b : whh_f;
    const float* h0  = d ? h0_b : h0_f;
    const float* c0  = d ? c0_b : c0_f;
    float* hs        = d ? hs_b : hs_f;

    const int l = threadIdx.x;       // 0..63
    const int r = l >> 1;            // local row 0..31 (gate-major)
    const int half = l & 1;          // k-half: [half*128, half*128+128)
    const int g = r >> 3, cl = r & 7;
    const int grow = g * 256 + cell0 + cl;   // global gate row (0..1023)

    __shared__ __align__(16) float w_lds[32][260];   // 33,280 B
    __shared__ __align__(16) float h_lds[256];

    // one-time weight load: thread (r, half) stages 128 f32
    {
        const float4* src = (const float4*)(whh + (size_t)grow * H2N + half * 128);
        float4* dst = (float4*)(&w_lds[r][half * 128]);
#pragma unroll
        for (int j = 0; j < 32; j++) dst[j] = src[j];
    }
    ((float4*)h_lds)[l] = ((const float4*)h0)[l];    // 64 x 16B = 1 KB
    float c = (l < 8) ? c0[cell0 + l] : 0.f;
    __syncthreads();

    const float* pre_base = pre + grow;
    float pre_cur = (half == 0) ? pre_base[0] : 0.f;
    const int ai = l & 7;            // activation cell index (lanes 0..7 use it)

    for (int t = 0; t < SLEN; t++) {
        float pre_next = (half == 0 && t < SLEN - 1) ? pre_base[(size_t)(t + 1) * G4] : 0.f;

        // dot over this thread's k-half: 32 x (w b128 + h b128 + 4 FMA chains)
        float a0 = pre_cur, a1 = 0.f, a2 = 0.f, a3 = 0.f;
        const float4* wrow4 = (const float4*)(&w_lds[r][half * 128]);
        const float4* hrow4 = (const float4*)(&h_lds[half * 128]);
#pragma unroll
        for (int j = 0; j < 32; j++) {
            float4 wv = wrow4[j];
            float4 hv = hrow4[j];
            a0 += wv.x * hv.x; a1 += wv.y * hv.y;
            a2 += wv.z * hv.z; a3 += wv.w * hv.w;
        }
        float sum = (a0 + a1) + (a2 + a3);
        sum += __shfl_xor(sum, 1, 64);   // combine k-halves; row r sum at lanes 2r,2r+1

        // gather the 4 gate sums for cell ai (rows ai, 8+ai, 16+ai, 24+ai)
        float s_i = __shfl(sum, 2 * ai, 64);
        float s_f = __shfl(sum, 16 + 2 * ai, 64);
        float s_g = __shfl(sum, 32 + 2 * ai, 64);
        float s_o = __shfl(sum, 48 + 2 * ai, 64);

        if (l < 8) {
            float i_ = fast_sigmoid(s_i);
            float f_ = fast_sigmoid(s_f);
            float g_ = fast_tanh(s_g);
            float o_ = fast_sigmoid(s_o);
            c = f_ * c + i_ * g_;
            float h = o_ * fast_tanh(c);
            unsigned hm = __float_as_uint(h) | 1u;   // flag bit, <=1 ulp
            __hip_atomic_store((unsigned*)hs + (size_t)t * H2N + cell0 + l, hm,
                               __ATOMIC_RELAXED, __HIP_MEMORY_SCOPE_AGENT);
        }

        // every lane pulls 4 cells (covers all 256, incl. our own 8)
        const unsigned* hsrc = (const unsigned*)hs + (size_t)t * H2N + 4 * l;
        unsigned v0, v1, v2, v3;
        int spin = 0;
        do {
            v0 = __hip_atomic_load(hsrc + 0, __ATOMIC_RELAXED, __HIP_MEMORY_SCOPE_AGENT);
            v1 = __hip_atomic_load(hsrc + 1, __ATOMIC_RELAXED, __HIP_MEMORY_SCOPE_AGENT);
            v2 = __hip_atomic_load(hsrc + 2, __ATOMIC_RELAXED, __HIP_MEMORY_SCOPE_AGENT);
            v3 = __hip_atomic_load(hsrc + 3, __ATOMIC_RELAXED, __HIP_MEMORY_SCOPE_AGENT);
        } while (((v0 & v1 & v2 & v3 & 1u) == 0u) && ++spin < 2000000);

        float4 hv4;
        hv4.x = __uint_as_float(v0); hv4.y = __uint_as_float(v1);
        hv4.z = __uint_as_float(v2); hv4.w = __uint_as_float(v3);
        *(float4*)(h_lds + 4 * l) = hv4;
        __syncthreads();             // single wave: lgkm drain + barrier
        pre_cur = pre_next;
    }
}

// ---------------- K3: feats = concat(hs_f[s], hs_b[S-1-s]) @ w_out^T + b_out ----------------
__global__ __launch_bounds__(256) void feats_kernel(
    const float* __restrict__ hs_f, const float* __restrict__ hs_b,
    const float* __restrict__ w_out, const float* __restrict__ b_out,
    float* __restrict__ feats)
{
    const int rs0 = blockIdx.x * 16;
    const int tid = threadIdx.x;
    const int r = tid >> 4, cc = tid & 15;

    __shared__ float Hs[16][513];
    for (int i = tid; i < 16 * 256; i += 256) {
        int rr = i >> 8, k = i & 255;
        Hs[rr][k]       = hs_f[(size_t)(rs0 + rr) * H2N + k];
        Hs[rr][256 + k] = hs_b[(size_t)(SLEN - 1 - (rs0 + rr)) * H2N + k];
    }
    __syncthreads();

    float acc = 0.f;
    const float* wr = w_out + (size_t)cc * 512;
#pragma unroll 8
    for (int k = 0; k < 512; k++) acc += Hs[r][k] * wr[k];
    feats[(size_t)(rs0 + r) * NTAG + cc] = acc + b_out[cc];
}

// ---------------- K4: Viterbi scan + backtrack (single wave) ----------------
__global__ __launch_bounds__(64) void viterbi_kernel(
    const float* __restrict__ feats, const float* __restrict__ trans,
    unsigned char* __restrict__ back, float* __restrict__ out)
{
    const int lane = threadIdx.x;
    const int nx = lane >> 2, pc = lane & 3;   // next tag, prev-chunk

    float tr[4];
#pragma unroll
    for (int j = 0; j < 4; j++) tr[j] = trans[nx * NTAG + pc * 4 + j];

    // score of tag g lives (replicated) in lanes 4g..4g+3
    float sc = (nx == 0) ? 0.f : NEGV;
    float fe = feats[nx];   // prefetch t=0

    for (int t = 0; t < SLEN; t++) {
        float fe_next = (t < SLEN - 1) ? feats[(size_t)(t + 1) * NTAG + nx] : 0.f;

        float bv; int bi;
#pragma unroll
        for (int j = 0; j < 4; j++) {
            float s = __shfl(sc, 4 * (pc * 4 + j), 64);
            float cand = s + tr[j];
            if (j == 0) { bv = cand; bi = pc * 4; }
            else if (cand > bv) { bv = cand; bi = pc * 4 + j; }
        }
        // combine across the 4 prev-chunks; first-max semantics (tie -> smaller idx)
#pragma unroll
        for (int off = 1; off < 4; off <<= 1) {
            float ov = __shfl_xor(bv, off, 64);
            int   oi = __shfl_xor(bi, off, 64);
            if (ov > bv || (ov == bv && oi < bi)) { bv = ov; bi = oi; }
        }
        if (pc == 0) back[(size_t)t * NTAG + nx] = (unsigned char)bi;
        sc = bv + fe;
        fe = fe_next;
    }

    // final = last + trans[END=1]; first-argmax
    float bestv = 0.f; int besti = 0;
#pragma unroll
    for (int j = 0; j < NTAG; j++) {
        float sj = __shfl(sc, 4 * j, 64);
        float fj = sj + trans[1 * NTAG + j];
        if (j == 0) { bestv = fj; besti = 0; }
        else if (fj > bestv) { bestv = fj; besti = j; }
    }

    if (lane == 0) {
        out[0] = bestv;
        int cur = besti;
        for (int t = SLEN - 1; t >= 1; t--) {
            out[1 + t] = (float)cur;
            cur = back[(size_t)t * NTAG + cur];
        }
        out[1] = (float)cur;
    }
}

extern "C" void kernel_launch(void* const* d_in, const int* in_sizes, int n_in,
                              void* d_out, int out_size, void* d_ws, size_t ws_size,
                              hipStream_t stream) {
    const int*   sent   = (const int*)d_in[0];
    const float* emb    = (const float*)d_in[1];
    const float* w_ih_f = (const float*)d_in[2];
    const float* w_hh_f = (const float*)d_in[3];
    const float* b_f    = (const float*)d_in[4];
    const float* w_ih_b = (const float*)d_in[5];
    const float* w_hh_b = (const float*)d_in[6];
    const float* b_b    = (const float*)d_in[7];
    const float* h0_f   = (const float*)d_in[8];
    const float* c0_f   = (const float*)d_in[9];
    const float* h0_b   = (const float*)d_in[10];
    const float* c0_b   = (const float*)d_in[11];
    const float* w_out  = (const float*)d_in[12];
    const float* b_out  = (const float*)d_in[13];
    const float* trans  = (const float*)d_in[14];
    float* out = (float*)d_out;

    if (ws_size < WS_NEEDED) return;  // visible failure, no OOB writes

    float* ws = (float*)d_ws;
    float* pre_f = ws + OFF_PRE_F;
    float* pre_b = ws + OFF_PRE_B;
    float* hs_f  = ws + OFF_HS_F;
    float* hs_b  = ws + OFF_HS_B;
    float* feats = ws + OFF_FEATS;
    unsigned char* back = (unsigned char*)d_ws + OFF_BACK_B;

    gemm_pre<<<dim3(128, 16, 2), 256, 0, stream>>>(sent, emb, w_ih_f, b_f, w_ih_b, b_b, pre_f, pre_b);
    lstm_kernel<<<64, 64, 0, stream>>>(pre_f, pre_b, w_hh_f, w_hh_b,
                                       h0_f, c0_f, h0_b, c0_b, hs_f, hs_b);
    feats_kernel<<<512, 256, 0, stream>>>(hs_f, hs_b, w_out, b_out, feats);
    viterbi_kernel<<<1, 64, 0, stream>>>(feats, trans, back, out);
}